// Round 1
// baseline (188.569 us; speedup 1.0000x reference)
//
#include <hip/hip_runtime.h>

// Levenshtein edit distance, ref (512,B) x hyp (512,B), B=1024, unit costs.
// Strategy: anti-diagonal wavefront, one 64-lane wave per batch element.
// Each lane holds 8 diagonal cells (i = lane*8+k+1) in registers.
// Values stored relative to the diagonal index d (v' = v - d):
//   new'[i] = min(D1'[i-1], D1'[i], D2'[i-1] + (ref_i==hyp_{d-i} ? -2 : -1))
// Top injection (i=0 boundary) is the constant 0; j=0 boundary emerges
// automatically from LARGE-initialized registers (frontier computes rel 0).

#define RLEN 512
#define HLEN 512
#define BATCH 1024
#define LARGE (1 << 20)

// One diagonal step. A2 = diag d-2 (rel d-2), A1 = diag d-1 (rel d-1),
// AN = output diag d (rel d). Also shifts the hyp-token queue and injects
// tok_inject at cell 0 (for step d+1).
#define STEP(A2, A1, AN, tok_inject)                                  \
  {                                                                   \
    int up1 = __shfl_up(A1[7], 1);                                    \
    int up2 = __shfl_up(A2[7], 1);                                    \
    int uph = __shfl_up(ht[7], 1);                                    \
    int a1m = (lane == 0) ? 0 : up1; /* D1'[i-1] for k==0 */          \
    int a2m = (lane == 0) ? 0 : up2; /* D2'[i-1] for k==0 */          \
    _Pragma("unroll")                                                 \
    for (int k = 0; k < 8; ++k) {                                     \
      int d1im = (k == 0) ? a1m : A1[k - 1];                          \
      int d2im = (k == 0) ? a2m : A2[k - 1];                          \
      int nm2 = (rt[k] == ht[k]) ? -2 : -1;                           \
      int cand = d2im + nm2;                                          \
      AN[k] = min(min(d1im, A1[k]), cand);                            \
    }                                                                 \
    _Pragma("unroll")                                                 \
    for (int k = 7; k >= 1; --k) ht[k] = ht[k - 1];                   \
    ht[0] = (lane == 0) ? (tok_inject) : uph;                         \
  }

__global__ __launch_bounds__(64, 1)
void edit_distance_kernel(const int* __restrict__ ref,
                          const int* __restrict__ hyp,
                          float* __restrict__ out) {
  const int b = blockIdx.x;        // one wave (block of 64) per batch element
  const int lane = threadIdx.x;    // 0..63

  // Static ref tokens for this wave's cells c = lane*8+k  (i = c+1).
  int rt[8];
#pragma unroll
  for (int k = 0; k < 8; ++k)
    rt[k] = ref[(lane * 8 + k) * BATCH + b];

  // Three rotating diagonal buffers (relative domain).
  int A[8], Bv[8], Cv[8];
#pragma unroll
  for (int k = 0; k < 8; ++k) { A[k] = LARGE; Bv[k] = LARGE; }
  if (lane == 0) Bv[0] = 0;  // D[1][0]=1, rel diag d=1 -> 0

  // Hyp token queue: ht[k] = token for cell c at current step d = hyp0[d-c-2].
  int ht[8];
#pragma unroll
  for (int k = 0; k < 8; ++k) ht[k] = -1;
  if (lane == 0) ht[0] = hyp[b];  // hyp0[0], consumed by cell 0 at d=2

  // Scalar-prefetched injection tokens: step d injects hyp0[d-1] (clamped).
  int d = 2;
  int t0 = hyp[min(d - 1, HLEN - 1) * BATCH + b];
  int t1 = hyp[min(d + 0, HLEN - 1) * BATCH + b];
  int t2 = hyp[min(d + 1, HLEN - 1) * BATCH + b];

  // 1023 diagonal steps (d = 2..1024), 3 per iteration, 341 iterations.
  for (int it = 0; it < 341; ++it) {
    int n0 = hyp[min(d + 2, HLEN - 1) * BATCH + b];
    int n1 = hyp[min(d + 3, HLEN - 1) * BATCH + b];
    int n2 = hyp[min(d + 4, HLEN - 1) * BATCH + b];
    STEP(A, Bv, Cv, t0);   // diag d
    STEP(Bv, Cv, A, t1);   // diag d+1
    STEP(Cv, A, Bv, t2);   // diag d+2
    d += 3;
    t0 = n0; t1 = n1; t2 = n2;
  }

  // Answer: D[512][512] on diag 1024 = Bv (last write), cell 511 = lane 63 k=7.
  if (lane == 63) out[b] = (float)(Bv[7] + (RLEN + HLEN));
}

extern "C" void kernel_launch(void* const* d_in, const int* in_sizes, int n_in,
                              void* d_out, int out_size, void* d_ws, size_t ws_size,
                              hipStream_t stream) {
  const int* ref = (const int*)d_in[0];
  const int* hyp = (const int*)d_in[1];
  float* out = (float*)d_out;
  edit_distance_kernel<<<BATCH, 64, 0, stream>>>(ref, hyp, out);
}